// Round 1
// baseline (450.623 us; speedup 1.0000x reference)
//
#include <hip/hip_runtime.h>
#include <cstdint>

#define B_    8
#define NCTX  2048
#define CIN   512
#define DHEAD 64
#define HID   512
#define O3    1536

typedef __bf16 bf16x8 __attribute__((ext_vector_type(8)));
typedef float  f32x4  __attribute__((ext_vector_type(4)));

__device__ inline unsigned short f2bf(float f) {
  unsigned u = __float_as_uint(f);
  u += 0x7fffu + ((u >> 16) & 1u);
  return (unsigned short)(u >> 16);
}

// async global->LDS, 16B per lane; lds base must be wave-uniform, dest = base + lane*16
__device__ inline void gload_lds16(const void* g, void* l) {
  __builtin_amdgcn_global_load_lds((const __attribute__((address_space(1))) unsigned int*)g,
                                   (__attribute__((address_space(3))) unsigned int*)l,
                                   16, 0, 0);
}

// swizzled index into a [rows][128] ushort LDS tile (16B chunks XORed by row&7)
__device__ inline int swidx128(int row, int col) {
  return row * 128 + ((((col >> 3) ^ (row & 7))) << 3) + (col & 7);
}

// ---------------- kernel A: x[b,c,t] fp32 -> xT[b,t,c] bf16 ----------------
__global__ __launch_bounds__(256) void k_transpose_x(const float* __restrict__ x,
                                                     unsigned short* __restrict__ xT) {
  __shared__ unsigned short tile[64][66];
  const int b  = blockIdx.z;
  const int t0 = blockIdx.x * 64;
  const int c0 = blockIdx.y * 64;
  const int tid = threadIdx.x;
  const int jj = (tid & 15) * 4;   // t within tile
  const int i0 = tid >> 4;         // c within tile
  const float* xb = x + ((size_t)b * CIN + c0) * NCTX + t0;
  #pragma unroll
  for (int s = 0; s < 4; ++s) {
    const int i = i0 + s * 16;
    const float4 v = *(const float4*)(xb + (size_t)i * NCTX + jj);
    tile[jj + 0][i] = f2bf(v.x);
    tile[jj + 1][i] = f2bf(v.y);
    tile[jj + 2][i] = f2bf(v.z);
    tile[jj + 3][i] = f2bf(v.w);
  }
  __syncthreads();
  const int ii = (tid & 15) * 4;   // c
  const int j0 = tid >> 4;         // t
  unsigned short* out = xT + ((size_t)b * NCTX + t0) * CIN + c0;
  #pragma unroll
  for (int s = 0; s < 4; ++s) {
    const int j = j0 + s * 16;
    ushort4 o;
    o.x = tile[j][ii + 0]; o.y = tile[j][ii + 1];
    o.z = tile[j][ii + 2]; o.w = tile[j][ii + 3];
    *(ushort4*)(out + (size_t)j * CIN + ii) = o;
  }
}

// ---------------- kernel B: fp32 -> bf16 weight convert ----------------
__global__ __launch_bounds__(256) void k_cvt_w(const float* __restrict__ wq,
                                               const float* __restrict__ wo,
                                               unsigned short* __restrict__ wq_bf,
                                               unsigned short* __restrict__ wo_bf) {
  const int i = (blockIdx.x * 256 + threadIdx.x) * 4;
  if (i < O3 * CIN) {
    const float4 v = *(const float4*)(wq + i);
    ushort4 o;
    o.x = f2bf(v.x); o.y = f2bf(v.y); o.z = f2bf(v.z); o.w = f2bf(v.w);
    *(ushort4*)(wq_bf + i) = o;
  } else {
    const int j = i - O3 * CIN;
    const float4 v = *(const float4*)(wo + j);
    ushort4 o;
    o.x = f2bf(v.x); o.y = f2bf(v.y); o.z = f2bf(v.z); o.w = f2bf(v.w);
    *(ushort4*)(wo_bf + j) = o;
  }
}

// ---------------- kernel C: QKV GEMM ----------------
// C[t,o] = sum_c xT[b,t,c] * wq[o,c];  M=2048 N=1536 K=512, batched over b
// writes Qt/Kt/Vt as [b,h,t,64] bf16, q scaled by 0.125*log2(e)
__global__ __launch_bounds__(256) void k_qkv(const unsigned short* __restrict__ xT,
                                             const unsigned short* __restrict__ wq,
                                             unsigned short* __restrict__ Qt,
                                             unsigned short* __restrict__ Kt,
                                             unsigned short* __restrict__ Vt) {
  __shared__ unsigned short As[128 * 64];
  __shared__ unsigned short Bs[128 * 64];
  const int b = blockIdx.z;
  const int tid = threadIdx.x;
  const int w = tid >> 6, L = tid & 63;
  const int m0 = (w & 1) * 64, n0 = (w >> 1) * 64;
  const unsigned short* Abase = xT + ((size_t)b * NCTX + blockIdx.x * 128) * CIN;
  const unsigned short* Bbase = wq + (size_t)blockIdx.y * 128 * CIN;

  f32x4 acc[4][4];
  #pragma unroll
  for (int i = 0; i < 4; ++i)
    #pragma unroll
    for (int j = 0; j < 4; ++j) acc[i][j] = f32x4{0.f, 0.f, 0.f, 0.f};

  const int sr = L >> 3;   // row within 8-row staging group
  const int pc = L & 7;    // physical 16B chunk

  for (int k0 = 0; k0 < CIN; k0 += 64) {
    __syncthreads();
    #pragma unroll
    for (int s = 0; s < 4; ++s) {
      const int r0 = s * 32 + w * 8;
      const int row = r0 + sr;
      const int cc = pc ^ (row & 7);
      gload_lds16(Abase + (size_t)row * CIN + k0 + cc * 8, &As[r0 * 64]);
      gload_lds16(Bbase + (size_t)row * CIN + k0 + cc * 8, &Bs[r0 * 64]);
    }
    __syncthreads();
    #pragma unroll
    for (int kc = 0; kc < 2; ++kc) {
      const int ccf = kc * 4 + (L >> 4);
      bf16x8 af[4], bfr[4];
      #pragma unroll
      for (int mt = 0; mt < 4; ++mt) {
        const int m = m0 + mt * 16 + (L & 15);
        af[mt] = *(const bf16x8*)&As[m * 64 + ((ccf ^ (m & 7)) * 8)];
      }
      #pragma unroll
      for (int nt = 0; nt < 4; ++nt) {
        const int n = n0 + nt * 16 + (L & 15);
        bfr[nt] = *(const bf16x8*)&Bs[n * 64 + ((ccf ^ (n & 7)) * 8)];
      }
      #pragma unroll
      for (int mt = 0; mt < 4; ++mt)
        #pragma unroll
        for (int nt = 0; nt < 4; ++nt)
          acc[mt][nt] = __builtin_amdgcn_mfma_f32_16x16x32_bf16(af[mt], bfr[nt], acc[mt][nt], 0, 0, 0);
    }
  }

  const float QS = 0.125f * 1.4426950408889634f;  // scale * log2(e), folded so softmax uses exp2
  #pragma unroll
  for (int mt = 0; mt < 4; ++mt) {
    #pragma unroll
    for (int nt = 0; nt < 4; ++nt) {
      const int o = blockIdx.y * 128 + n0 + nt * 16 + (L & 15);
      const int which = o >> 9;
      const int h = (o >> 6) & 7;
      const int d = o & 63;
      unsigned short* base = (which == 0) ? Qt : ((which == 1) ? Kt : Vt);
      unsigned short* dst = base + (((size_t)b * 8 + h) * NCTX) * 64 + d;
      const float scale = (which == 0) ? QS : 1.0f;
      #pragma unroll
      for (int r = 0; r < 4; ++r) {
        const int t = blockIdx.x * 128 + m0 + mt * 16 + (L >> 4) * 4 + r;
        dst[(size_t)t * 64] = f2bf(acc[mt][nt][r] * scale);
      }
    }
  }
}

// ---------------- kernel D: flash attention ----------------
// per (b,h): S = Qt.Kt^T (pre-scaled), online softmax (exp2 domain), O = P.V
// AO[b,t,h*64+dv] bf16
__global__ __launch_bounds__(256) void k_attn(const unsigned short* __restrict__ Qt,
                                              const unsigned short* __restrict__ Kt,
                                              const unsigned short* __restrict__ Vt,
                                              unsigned short* __restrict__ AO) {
  __shared__ unsigned short Ks[128 * 64];     // [j][d] swizzled
  __shared__ unsigned short Vs[64 * 128];     // [dv][j] swizzled (transposed)
  __shared__ unsigned short Ps[4][32 * 128];  // per-wave P, swizzled
  const int bh = blockIdx.y;
  const int q0 = blockIdx.x * 128;
  const int tid = threadIdx.x;
  const int w = tid >> 6, L = tid & 63;
  const unsigned short* Qb = Qt + (size_t)bh * NCTX * 64;
  const unsigned short* Kb = Kt + (size_t)bh * NCTX * 64;
  const unsigned short* Vb = Vt + (size_t)bh * NCTX * 64;

  bf16x8 qf[2][2];
  #pragma unroll
  for (int mt = 0; mt < 2; ++mt)
    #pragma unroll
    for (int kc = 0; kc < 2; ++kc) {
      const int row = q0 + w * 32 + mt * 16 + (L & 15);
      qf[mt][kc] = *(const bf16x8*)(Qb + (size_t)row * 64 + kc * 32 + (L >> 4) * 8);
    }

  f32x4 oacc[2][4];
  #pragma unroll
  for (int mt = 0; mt < 2; ++mt)
    #pragma unroll
    for (int dt = 0; dt < 4; ++dt) oacc[mt][dt] = f32x4{0.f, 0.f, 0.f, 0.f};
  float m_i[2][4], l_i[2][4];
  #pragma unroll
  for (int mt = 0; mt < 2; ++mt)
    #pragma unroll
    for (int r = 0; r < 4; ++r) { m_i[mt][r] = -1e30f; l_i[mt][r] = 0.f; }

  const int sr = L >> 3, pc = L & 7;

  for (int jt = 0; jt < 16; ++jt) {
    const int j0 = jt * 128;
    __syncthreads();
    // K tile via async copy (swizzled)
    #pragma unroll
    for (int s = 0; s < 4; ++s) {
      const int r0 = s * 32 + w * 8;
      const int row = r0 + sr;
      gload_lds16(Kb + (size_t)(j0 + row) * 64 + ((pc ^ (row & 7)) * 8), &Ks[r0 * 64]);
    }
    // V tile: load [j][dv], store transposed [dv][j]
    #pragma unroll
    for (int s = 0; s < 4; ++s) {
      const int j = L + 64 * (s & 1);
      const int pcv = w + 4 * (s >> 1);
      const uint4 raw = *(const uint4*)(Vb + (size_t)(j0 + j) * 64 + pcv * 8);
      const unsigned vals[4] = {raw.x, raw.y, raw.z, raw.w};
      #pragma unroll
      for (int e2 = 0; e2 < 4; ++e2) {
        const int dv0 = pcv * 8 + e2 * 2;
        Vs[swidx128(dv0, j)]     = (unsigned short)(vals[e2] & 0xffffu);
        Vs[swidx128(dv0 + 1, j)] = (unsigned short)(vals[e2] >> 16);
      }
    }
    __syncthreads();

    // S = Q.K^T  (32 rows per wave x 128 cols)
    f32x4 sacc[2][8];
    #pragma unroll
    for (int nt = 0; nt < 8; ++nt) {
      const int n = nt * 16 + (L & 15);
      const int cg = L >> 4;
      const bf16x8 kf0 = *(const bf16x8*)&Ks[n * 64 + ((cg ^ (n & 7)) * 8)];
      const bf16x8 kf1 = *(const bf16x8*)&Ks[n * 64 + (((4 + cg) ^ (n & 7)) * 8)];
      #pragma unroll
      for (int mt = 0; mt < 2; ++mt) {
        f32x4 z = f32x4{0.f, 0.f, 0.f, 0.f};
        z = __builtin_amdgcn_mfma_f32_16x16x32_bf16(qf[mt][0], kf0, z, 0, 0, 0);
        sacc[mt][nt] = __builtin_amdgcn_mfma_f32_16x16x32_bf16(qf[mt][1], kf1, z, 0, 0, 0);
      }
    }

    // online softmax (exp2 domain; log2e folded into q scale)
    float mnew[2][4], alpha[2][4], rs[2][4];
    #pragma unroll
    for (int mt = 0; mt < 2; ++mt)
      #pragma unroll
      for (int r = 0; r < 4; ++r) {
        float rm = sacc[mt][0][r];
        #pragma unroll
        for (int nt = 1; nt < 8; ++nt) rm = fmaxf(rm, sacc[mt][nt][r]);
        rm = fmaxf(rm, __shfl_xor(rm, 1, 64));
        rm = fmaxf(rm, __shfl_xor(rm, 2, 64));
        rm = fmaxf(rm, __shfl_xor(rm, 4, 64));
        rm = fmaxf(rm, __shfl_xor(rm, 8, 64));
        const float mn = fmaxf(m_i[mt][r], rm);
        mnew[mt][r] = mn;
        alpha[mt][r] = exp2f(m_i[mt][r] - mn);
        m_i[mt][r] = mn;
        rs[mt][r] = 0.f;
      }
    const int prow_base = (L >> 4) * 4;
    const int pcol = L & 15;
    #pragma unroll
    for (int mt = 0; mt < 2; ++mt)
      #pragma unroll
      for (int nt = 0; nt < 8; ++nt)
        #pragma unroll
        for (int r = 0; r < 4; ++r) {
          const float p = exp2f(sacc[mt][nt][r] - mnew[mt][r]);
          rs[mt][r] += p;
          Ps[w][swidx128(mt * 16 + prow_base + r, nt * 16 + pcol)] = f2bf(p);
        }
    #pragma unroll
    for (int mt = 0; mt < 2; ++mt)
      #pragma unroll
      for (int r = 0; r < 4; ++r) {
        float t = rs[mt][r];
        t += __shfl_xor(t, 1, 64);
        t += __shfl_xor(t, 2, 64);
        t += __shfl_xor(t, 4, 64);
        t += __shfl_xor(t, 8, 64);
        l_i[mt][r] = l_i[mt][r] * alpha[mt][r] + t;
        #pragma unroll
        for (int dt = 0; dt < 4; ++dt) oacc[mt][dt][r] *= alpha[mt][r];
      }

    // O += P.V
    bf16x8 pf[2][4];
    #pragma unroll
    for (int mt = 0; mt < 2; ++mt)
      #pragma unroll
      for (int kc = 0; kc < 4; ++kc) {
        const int m = mt * 16 + (L & 15);
        const int cc = kc * 4 + (L >> 4);
        pf[mt][kc] = *(const bf16x8*)&Ps[w][m * 128 + ((cc ^ (m & 7)) * 8)];
      }
    #pragma unroll
    for (int dt = 0; dt < 4; ++dt) {
      bf16x8 vf[4];
      #pragma unroll
      for (int kc = 0; kc < 4; ++kc) {
        const int n = dt * 16 + (L & 15);
        const int cc = kc * 4 + (L >> 4);
        vf[kc] = *(const bf16x8*)&Vs[n * 128 + ((cc ^ (n & 7)) * 8)];
      }
      #pragma unroll
      for (int mt = 0; mt < 2; ++mt)
        #pragma unroll
        for (int kc = 0; kc < 4; ++kc)
          oacc[mt][dt] = __builtin_amdgcn_mfma_f32_16x16x32_bf16(pf[mt][kc], vf[kc], oacc[mt][dt], 0, 0, 0);
    }
  }

  const int b = bh >> 3, h = bh & 7;
  #pragma unroll
  for (int mt = 0; mt < 2; ++mt)
    #pragma unroll
    for (int r = 0; r < 4; ++r) {
      const float inv = 1.0f / l_i[mt][r];
      const int t = q0 + w * 32 + mt * 16 + (L >> 4) * 4 + r;
      #pragma unroll
      for (int dt = 0; dt < 4; ++dt) {
        const int dv = dt * 16 + (L & 15);
        AO[((size_t)b * NCTX + t) * HID + h * 64 + dv] = f2bf(oacc[mt][dt][r] * inv);
      }
    }
}

// ---------------- kernel E: output projection ----------------
// y[b,o,t] = sum_k wo[o,k] * AO[b,t,k] + bias[o];  M=512 N=2048 K=512
__global__ __launch_bounds__(256) void k_proj(const unsigned short* __restrict__ wo,
                                              const unsigned short* __restrict__ AO,
                                              const float* __restrict__ bias,
                                              float* __restrict__ y) {
  __shared__ unsigned short As[128 * 64];
  __shared__ unsigned short Bs[128 * 64];
  const int b = blockIdx.z;
  const int tid = threadIdx.x;
  const int w = tid >> 6, L = tid & 63;
  const int m0 = (w & 1) * 64, n0 = (w >> 1) * 64;
  const unsigned short* Abase = wo + (size_t)blockIdx.x * 128 * HID;
  const unsigned short* Bbase = AO + ((size_t)b * NCTX + blockIdx.y * 128) * HID;

  f32x4 acc[4][4];
  #pragma unroll
  for (int i = 0; i < 4; ++i)
    #pragma unroll
    for (int j = 0; j < 4; ++j) acc[i][j] = f32x4{0.f, 0.f, 0.f, 0.f};

  const int sr = L >> 3;
  const int pc = L & 7;
  for (int k0 = 0; k0 < HID; k0 += 64) {
    __syncthreads();
    #pragma unroll
    for (int s = 0; s < 4; ++s) {
      const int r0 = s * 32 + w * 8;
      const int row = r0 + sr;
      const int cc = pc ^ (row & 7);
      gload_lds16(Abase + (size_t)row * HID + k0 + cc * 8, &As[r0 * 64]);
      gload_lds16(Bbase + (size_t)row * HID + k0 + cc * 8, &Bs[r0 * 64]);
    }
    __syncthreads();
    #pragma unroll
    for (int kc = 0; kc < 2; ++kc) {
      const int ccf = kc * 4 + (L >> 4);
      bf16x8 af[4], bfr[4];
      #pragma unroll
      for (int mt = 0; mt < 4; ++mt) {
        const int m = m0 + mt * 16 + (L & 15);
        af[mt] = *(const bf16x8*)&As[m * 64 + ((ccf ^ (m & 7)) * 8)];
      }
      #pragma unroll
      for (int nt = 0; nt < 4; ++nt) {
        const int n = n0 + nt * 16 + (L & 15);
        bfr[nt] = *(const bf16x8*)&Bs[n * 64 + ((ccf ^ (n & 7)) * 8)];
      }
      #pragma unroll
      for (int mt = 0; mt < 4; ++mt)
        #pragma unroll
        for (int nt = 0; nt < 4; ++nt)
          acc[mt][nt] = __builtin_amdgcn_mfma_f32_16x16x32_bf16(af[mt], bfr[nt], acc[mt][nt], 0, 0, 0);
    }
  }

  #pragma unroll
  for (int mt = 0; mt < 4; ++mt) {
    #pragma unroll
    for (int nt = 0; nt < 4; ++nt) {
      const int t = blockIdx.y * 128 + n0 + nt * 16 + (L & 15);
      #pragma unroll
      for (int r = 0; r < 4; ++r) {
        const int o = blockIdx.x * 128 + m0 + mt * 16 + (L >> 4) * 4 + r;
        y[((size_t)b * CIN + o) * NCTX + t] = acc[mt][nt][r] + bias[o];
      }
    }
  }
}

extern "C" void kernel_launch(void* const* d_in, const int* in_sizes, int n_in,
                              void* d_out, int out_size, void* d_ws, size_t ws_size,
                              hipStream_t stream) {
  const float* x     = (const float*)d_in[0];
  const float* w_qkv = (const float*)d_in[1];
  const float* w_out = (const float*)d_in[2];
  const float* b_out = (const float*)d_in[3];
  float* y = (float*)d_out;

  char* ws = (char*)d_ws;
  const size_t SEG = (size_t)16 * 1024 * 1024;  // 16 MiB per bf16 tensor of 8.39M elems
  unsigned short* xT    = (unsigned short*)(ws + 0 * SEG);
  unsigned short* Qt    = (unsigned short*)(ws + 1 * SEG);
  unsigned short* Kt    = (unsigned short*)(ws + 2 * SEG);
  unsigned short* Vt    = (unsigned short*)(ws + 3 * SEG);
  unsigned short* AO    = (unsigned short*)(ws + 4 * SEG);
  unsigned short* wq_bf = (unsigned short*)(ws + 5 * SEG);
  unsigned short* wo_bf = (unsigned short*)(ws + 5 * SEG + (size_t)O3 * CIN * 2);

  k_transpose_x<<<dim3(32, 8, 8), 256, 0, stream>>>(x, xT);
  k_cvt_w<<<dim3(1024), 256, 0, stream>>>(w_qkv, w_out, wq_bf, wo_bf);
  k_qkv<<<dim3(16, 12, 8), 256, 0, stream>>>(xT, wq_bf, Qt, Kt, Vt);
  k_attn<<<dim3(16, 64), 256, 0, stream>>>(Qt, Kt, Vt, AO);
  k_proj<<<dim3(4, 16, 8), 256, 0, stream>>>(wo_bf, AO, b_out, y);
}

// Round 2
// 274.053 us; speedup vs baseline: 1.6443x; 1.6443x over previous
//
#include <hip/hip_runtime.h>
#include <cstdint>

#define B_    8
#define NCTX  2048
#define CIN   512
#define DHEAD 64
#define HID   512
#define O3    1536

typedef __bf16 bf16x8 __attribute__((ext_vector_type(8)));
typedef short  s16x4  __attribute__((ext_vector_type(4)));
typedef float  f32x4  __attribute__((ext_vector_type(4)));

__device__ inline unsigned short f2bf(float f) {
  unsigned u = __float_as_uint(f);
  u += 0x7fffu + ((u >> 16) & 1u);
  return (unsigned short)(u >> 16);
}

// pack two fp32 -> bf16x2 (round half-up), a in low 16, b in high 16 (one v_perm)
__device__ inline unsigned pack_bf16(float a, float b) {
  const unsigned ua = __float_as_uint(a) + 0x8000u;
  const unsigned ub = __float_as_uint(b) + 0x8000u;
  return __builtin_amdgcn_perm(ub, ua, 0x07060302u);  // {hi16(ub), hi16(ua)}
}

// async global->LDS, 16B per lane; lds base must be wave-uniform, dest = base + lane*16
__device__ inline void gload_lds16(const void* g, void* l) {
  __builtin_amdgcn_global_load_lds((const __attribute__((address_space(1))) unsigned int*)g,
                                   (__attribute__((address_space(3))) unsigned int*)l,
                                   16, 0, 0);
}

// swizzled index into a [rows][128] ushort LDS tile (16B chunks XORed by row&7)
__device__ inline int swidx128(int row, int col) {
  return row * 128 + ((((col >> 3) ^ (row & 7))) << 3) + (col & 7);
}

// ---------------- kernel A: x[b,c,t] fp32 -> xT[b,t,c] bf16 ----------------
__global__ __launch_bounds__(256) void k_transpose_x(const float* __restrict__ x,
                                                     unsigned short* __restrict__ xT) {
  __shared__ unsigned short tile[64][66];
  const int b  = blockIdx.z;
  const int t0 = blockIdx.x * 64;
  const int c0 = blockIdx.y * 64;
  const int tid = threadIdx.x;
  const int jj = (tid & 15) * 4;   // t within tile
  const int i0 = tid >> 4;         // c within tile
  const float* xb = x + ((size_t)b * CIN + c0) * NCTX + t0;
  #pragma unroll
  for (int s = 0; s < 4; ++s) {
    const int i = i0 + s * 16;
    const float4 v = *(const float4*)(xb + (size_t)i * NCTX + jj);
    tile[jj + 0][i] = f2bf(v.x);
    tile[jj + 1][i] = f2bf(v.y);
    tile[jj + 2][i] = f2bf(v.z);
    tile[jj + 3][i] = f2bf(v.w);
  }
  __syncthreads();
  const int ii = (tid & 15) * 4;   // c
  const int j0 = tid >> 4;         // t
  unsigned short* out = xT + ((size_t)b * NCTX + t0) * CIN + c0;
  #pragma unroll
  for (int s = 0; s < 4; ++s) {
    const int j = j0 + s * 16;
    ushort4 o;
    o.x = tile[j][ii + 0]; o.y = tile[j][ii + 1];
    o.z = tile[j][ii + 2]; o.w = tile[j][ii + 3];
    *(ushort4*)(out + (size_t)j * CIN + ii) = o;
  }
}

// ---------------- kernel B: fp32 -> bf16 weight convert ----------------
__global__ __launch_bounds__(256) void k_cvt_w(const float* __restrict__ wq,
                                               const float* __restrict__ wo,
                                               unsigned short* __restrict__ wq_bf,
                                               unsigned short* __restrict__ wo_bf) {
  const int i = (blockIdx.x * 256 + threadIdx.x) * 4;
  if (i < O3 * CIN) {
    const float4 v = *(const float4*)(wq + i);
    ushort4 o;
    o.x = f2bf(v.x); o.y = f2bf(v.y); o.z = f2bf(v.z); o.w = f2bf(v.w);
    *(ushort4*)(wq_bf + i) = o;
  } else {
    const int j = i - O3 * CIN;
    const float4 v = *(const float4*)(wo + j);
    ushort4 o;
    o.x = f2bf(v.x); o.y = f2bf(v.y); o.z = f2bf(v.z); o.w = f2bf(v.w);
    *(ushort4*)(wo_bf + j) = o;
  }
}

// ---------------- kernel C: QKV GEMM ----------------
__global__ __launch_bounds__(256) void k_qkv(const unsigned short* __restrict__ xT,
                                             const unsigned short* __restrict__ wq,
                                             unsigned short* __restrict__ Qt,
                                             unsigned short* __restrict__ Kt,
                                             unsigned short* __restrict__ Vt) {
  __shared__ unsigned short As[128 * 64];
  __shared__ unsigned short Bs[128 * 64];
  const int b = blockIdx.z;
  const int tid = threadIdx.x;
  const int w = tid >> 6, L = tid & 63;
  const int m0 = (w & 1) * 64, n0 = (w >> 1) * 64;
  const unsigned short* Abase = xT + ((size_t)b * NCTX + blockIdx.x * 128) * CIN;
  const unsigned short* Bbase = wq + (size_t)blockIdx.y * 128 * CIN;

  f32x4 acc[4][4];
  #pragma unroll
  for (int i = 0; i < 4; ++i)
    #pragma unroll
    for (int j = 0; j < 4; ++j) acc[i][j] = f32x4{0.f, 0.f, 0.f, 0.f};

  const int sr = L >> 3;
  const int pc = L & 7;

  for (int k0 = 0; k0 < CIN; k0 += 64) {
    __syncthreads();
    #pragma unroll
    for (int s = 0; s < 4; ++s) {
      const int r0 = s * 32 + w * 8;
      const int row = r0 + sr;
      const int cc = pc ^ (row & 7);
      gload_lds16(Abase + (size_t)row * CIN + k0 + cc * 8, &As[r0 * 64]);
      gload_lds16(Bbase + (size_t)row * CIN + k0 + cc * 8, &Bs[r0 * 64]);
    }
    __syncthreads();
    #pragma unroll
    for (int kc = 0; kc < 2; ++kc) {
      const int ccf = kc * 4 + (L >> 4);
      bf16x8 af[4], bfr[4];
      #pragma unroll
      for (int mt = 0; mt < 4; ++mt) {
        const int m = m0 + mt * 16 + (L & 15);
        af[mt] = *(const bf16x8*)&As[m * 64 + ((ccf ^ (m & 7)) * 8)];
      }
      #pragma unroll
      for (int nt = 0; nt < 4; ++nt) {
        const int n = n0 + nt * 16 + (L & 15);
        bfr[nt] = *(const bf16x8*)&Bs[n * 64 + ((ccf ^ (n & 7)) * 8)];
      }
      #pragma unroll
      for (int mt = 0; mt < 4; ++mt)
        #pragma unroll
        for (int nt = 0; nt < 4; ++nt)
          acc[mt][nt] = __builtin_amdgcn_mfma_f32_16x16x32_bf16(af[mt], bfr[nt], acc[mt][nt], 0, 0, 0);
    }
  }

  const float QS = 0.125f * 1.4426950408889634f;  // scale * log2(e): softmax uses exp2
  #pragma unroll
  for (int mt = 0; mt < 4; ++mt) {
    #pragma unroll
    for (int nt = 0; nt < 4; ++nt) {
      const int o = blockIdx.y * 128 + n0 + nt * 16 + (L & 15);
      const int which = o >> 9;
      const int h = (o >> 6) & 7;
      const int d = o & 63;
      unsigned short* base = (which == 0) ? Qt : ((which == 1) ? Kt : Vt);
      unsigned short* dst = base + (((size_t)b * 8 + h) * NCTX) * 64 + d;
      const float scale = (which == 0) ? QS : 1.0f;
      #pragma unroll
      for (int r = 0; r < 4; ++r) {
        const int t = blockIdx.x * 128 + m0 + mt * 16 + (L >> 4) * 4 + r;
        dst[(size_t)t * 64] = f2bf(acc[mt][nt][r] * scale);
      }
    }
  }
}

// ---------------- kernel D: flash attention (register-resident P) ----------------
// Compute S^T = K.Q^T with 16x16x32 MFMA (A=K, B=Q). C-layout of S^T equals the
// B-operand layout of 16x16x16 MFMA (k=(l>>4)*4+r, n=l&15), so P^T fragments feed
// O^T = V^T . P^T directly from registers -- no P round trip through LDS.
__global__ __launch_bounds__(256) void k_attn(const unsigned short* __restrict__ Qt,
                                              const unsigned short* __restrict__ Kt,
                                              const unsigned short* __restrict__ Vt,
                                              unsigned short* __restrict__ AO) {
  __shared__ unsigned short Ks[128 * 64];   // [j][d] swizzled
  __shared__ unsigned short Vs[64 * 128];   // [d][j] swizzled (V transposed)
  const int bh = blockIdx.y;
  const int q0 = blockIdx.x * 128;
  const int tid = threadIdx.x;
  const int w = tid >> 6, L = tid & 63;
  const int g = L >> 4, lm = L & 15;
  const unsigned short* Qb = Qt + (size_t)bh * NCTX * 64;
  const unsigned short* Kb = Kt + (size_t)bh * NCTX * 64;
  const unsigned short* Vb = Vt + (size_t)bh * NCTX * 64;

  // Q fragments (B-operand of 16x16x32): n = lm (+16*it), k = d = kc*32 + g*8 + 0..7
  bf16x8 qf[2][2];
  #pragma unroll
  for (int it = 0; it < 2; ++it)
    #pragma unroll
    for (int kc = 0; kc < 2; ++kc) {
      const int row = q0 + w * 32 + it * 16 + lm;
      qf[it][kc] = *(const bf16x8*)(Qb + (size_t)row * 64 + kc * 32 + g * 8);
    }

  // O^T accumulators: oacc[dt][it], d = dt*16 + g*4 + r, i = it*16 + lm
  f32x4 oacc[4][2];
  #pragma unroll
  for (int dt = 0; dt < 4; ++dt)
    #pragma unroll
    for (int it = 0; it < 2; ++it) oacc[dt][it] = f32x4{0.f, 0.f, 0.f, 0.f};
  float m_st[2] = {-1e30f, -1e30f}, l_st[2] = {0.f, 0.f};

  const int sr = L >> 3, pc = L & 7;

  for (int jt = 0; jt < 16; ++jt) {
    const int j0 = jt * 128;
    __syncthreads();
    // stage K tile via async copy (swizzled)
    #pragma unroll
    for (int s = 0; s < 4; ++s) {
      const int r0 = s * 32 + w * 8;
      const int row = r0 + sr;
      gload_lds16(Kb + (size_t)(j0 + row) * 64 + ((pc ^ (row & 7)) * 8), &Ks[r0 * 64]);
    }
    // stage V transposed: [j][d] -> [d][j] swizzled
    #pragma unroll
    for (int s = 0; s < 4; ++s) {
      const int j = L + 64 * (s & 1);
      const int pcv = w + 4 * (s >> 1);
      const uint4 raw = *(const uint4*)(Vb + (size_t)(j0 + j) * 64 + pcv * 8);
      const unsigned vals[4] = {raw.x, raw.y, raw.z, raw.w};
      #pragma unroll
      for (int e2 = 0; e2 < 4; ++e2) {
        const int dv0 = pcv * 8 + e2 * 2;
        Vs[swidx128(dv0, j)]     = (unsigned short)(vals[e2] & 0xffffu);
        Vs[swidx128(dv0 + 1, j)] = (unsigned short)(vals[e2] >> 16);
      }
    }
    __syncthreads();

    // S^T = K.Q^T : sacc[jj][it] holds S^T[j = jj*16+g*4+r][i = it*16+lm]
    f32x4 sacc[8][2];
    #pragma unroll
    for (int jj = 0; jj < 8; ++jj) {
      const int n = jj * 16 + lm;  // j row of K
      const bf16x8 kf0 = *(const bf16x8*)&Ks[n * 64 + ((g ^ (n & 7)) << 3)];
      const bf16x8 kf1 = *(const bf16x8*)&Ks[n * 64 + (((4 + g) ^ (n & 7)) << 3)];
      #pragma unroll
      for (int it = 0; it < 2; ++it) {
        f32x4 z = f32x4{0.f, 0.f, 0.f, 0.f};
        z = __builtin_amdgcn_mfma_f32_16x16x32_bf16(kf0, qf[it][0], z, 0, 0, 0);
        sacc[jj][it] = __builtin_amdgcn_mfma_f32_16x16x32_bf16(kf1, qf[it][1], z, 0, 0, 0);
      }
    }

    // online softmax over j (regs + lane-groups); P^T packed to bf16 B-fragments
    s16x4 pf[8][2];
    #pragma unroll
    for (int it = 0; it < 2; ++it) {
      float rm = sacc[0][it][0];
      #pragma unroll
      for (int jj = 0; jj < 8; ++jj)
        #pragma unroll
        for (int r = 0; r < 4; ++r) rm = fmaxf(rm, sacc[jj][it][r]);
      rm = fmaxf(rm, __shfl_xor(rm, 16, 64));
      rm = fmaxf(rm, __shfl_xor(rm, 32, 64));
      const float mn = fmaxf(m_st[it], rm);
      const float alpha = __builtin_amdgcn_exp2f(m_st[it] - mn);
      m_st[it] = mn;
      float rsum = 0.f;
      #pragma unroll
      for (int jj = 0; jj < 8; ++jj) {
        float p[4];
        #pragma unroll
        for (int r = 0; r < 4; ++r) {
          p[r] = __builtin_amdgcn_exp2f(sacc[jj][it][r] - mn);
          rsum += p[r];
        }
        unsigned u32x2_v[2];
        u32x2_v[0] = pack_bf16(p[0], p[1]);
        u32x2_v[1] = pack_bf16(p[2], p[3]);
        pf[jj][it] = __builtin_bit_cast(s16x4, *(const uint2*)u32x2_v);
      }
      rsum += __shfl_xor(rsum, 16, 64);
      rsum += __shfl_xor(rsum, 32, 64);
      l_st[it] = l_st[it] * alpha + rsum;
      #pragma unroll
      for (int dt = 0; dt < 4; ++dt) {
        oacc[dt][it][0] *= alpha; oacc[dt][it][1] *= alpha;
        oacc[dt][it][2] *= alpha; oacc[dt][it][3] *= alpha;
      }
    }

    // O^T += V^T . P^T  (16x16x16, A = V^T from LDS, B = P^T from registers)
    #pragma unroll
    for (int jj = 0; jj < 8; ++jj) {
      #pragma unroll
      for (int dt = 0; dt < 4; ++dt) {
        const int d = dt * 16 + lm;
        const int addr = d * 128 + ((((jj * 2) + (g >> 1)) ^ (d & 7)) << 3) + ((g & 1) << 2);
        const s16x4 af = *(const s16x4*)&Vs[addr];
        #pragma unroll
        for (int it = 0; it < 2; ++it)
          oacc[dt][it] = __builtin_amdgcn_mfma_f32_16x16x16bf16_1k(af, pf[jj][it], oacc[dt][it], 0, 0, 0);
      }
    }
  }

  // epilogue: AO[b, t, h*64 + d] = O^T[d][i] / l_i
  const int b = bh >> 3, h = bh & 7;
  #pragma unroll
  for (int it = 0; it < 2; ++it) {
    const float inv = 1.0f / l_st[it];
    const int t = q0 + w * 32 + it * 16 + lm;
    #pragma unroll
    for (int dt = 0; dt < 4; ++dt) {
      uint2 o;
      o.x = pack_bf16(oacc[dt][it][0] * inv, oacc[dt][it][1] * inv);
      o.y = pack_bf16(oacc[dt][it][2] * inv, oacc[dt][it][3] * inv);
      *(uint2*)&AO[((size_t)b * NCTX + t) * HID + h * 64 + dt * 16 + g * 4] = o;
    }
  }
}

// ---------------- kernel E: output projection ----------------
__global__ __launch_bounds__(256) void k_proj(const unsigned short* __restrict__ wo,
                                              const unsigned short* __restrict__ AO,
                                              const float* __restrict__ bias,
                                              float* __restrict__ y) {
  __shared__ unsigned short As[128 * 64];
  __shared__ unsigned short Bs[128 * 64];
  const int b = blockIdx.z;
  const int tid = threadIdx.x;
  const int w = tid >> 6, L = tid & 63;
  const int m0 = (w & 1) * 64, n0 = (w >> 1) * 64;
  const unsigned short* Abase = wo + (size_t)blockIdx.x * 128 * HID;
  const unsigned short* Bbase = AO + ((size_t)b * NCTX + blockIdx.y * 128) * HID;

  f32x4 acc[4][4];
  #pragma unroll
  for (int i = 0; i < 4; ++i)
    #pragma unroll
    for (int j = 0; j < 4; ++j) acc[i][j] = f32x4{0.f, 0.f, 0.f, 0.f};

  const int sr = L >> 3;
  const int pc = L & 7;
  for (int k0 = 0; k0 < HID; k0 += 64) {
    __syncthreads();
    #pragma unroll
    for (int s = 0; s < 4; ++s) {
      const int r0 = s * 32 + w * 8;
      const int row = r0 + sr;
      const int cc = pc ^ (row & 7);
      gload_lds16(Abase + (size_t)row * HID + k0 + cc * 8, &As[r0 * 64]);
      gload_lds16(Bbase + (size_t)row * HID + k0 + cc * 8, &Bs[r0 * 64]);
    }
    __syncthreads();
    #pragma unroll
    for (int kc = 0; kc < 2; ++kc) {
      const int ccf = kc * 4 + (L >> 4);
      bf16x8 af[4], bfr[4];
      #pragma unroll
      for (int mt = 0; mt < 4; ++mt) {
        const int m = m0 + mt * 16 + (L & 15);
        af[mt] = *(const bf16x8*)&As[m * 64 + ((ccf ^ (m & 7)) * 8)];
      }
      #pragma unroll
      for (int nt = 0; nt < 4; ++nt) {
        const int n = n0 + nt * 16 + (L & 15);
        bfr[nt] = *(const bf16x8*)&Bs[n * 64 + ((ccf ^ (n & 7)) * 8)];
      }
      #pragma unroll
      for (int mt = 0; mt < 4; ++mt)
        #pragma unroll
        for (int nt = 0; nt < 4; ++nt)
          acc[mt][nt] = __builtin_amdgcn_mfma_f32_16x16x32_bf16(af[mt], bfr[nt], acc[mt][nt], 0, 0, 0);
    }
  }

  #pragma unroll
  for (int mt = 0; mt < 4; ++mt) {
    #pragma unroll
    for (int nt = 0; nt < 4; ++nt) {
      const int t = blockIdx.y * 128 + n0 + nt * 16 + (L & 15);
      #pragma unroll
      for (int r = 0; r < 4; ++r) {
        const int o = blockIdx.x * 128 + m0 + mt * 16 + (L >> 4) * 4 + r;
        y[((size_t)b * CIN + o) * NCTX + t] = acc[mt][nt][r] + bias[o];
      }
    }
  }
}

extern "C" void kernel_launch(void* const* d_in, const int* in_sizes, int n_in,
                              void* d_out, int out_size, void* d_ws, size_t ws_size,
                              hipStream_t stream) {
  const float* x     = (const float*)d_in[0];
  const float* w_qkv = (const float*)d_in[1];
  const float* w_out = (const float*)d_in[2];
  const float* b_out = (const float*)d_in[3];
  float* y = (float*)d_out;

  char* ws = (char*)d_ws;
  const size_t SEG = (size_t)16 * 1024 * 1024;
  unsigned short* xT    = (unsigned short*)(ws + 0 * SEG);
  unsigned short* Qt    = (unsigned short*)(ws + 1 * SEG);
  unsigned short* Kt    = (unsigned short*)(ws + 2 * SEG);
  unsigned short* Vt    = (unsigned short*)(ws + 3 * SEG);
  unsigned short* AO    = (unsigned short*)(ws + 4 * SEG);
  unsigned short* wq_bf = (unsigned short*)(ws + 5 * SEG);
  unsigned short* wo_bf = (unsigned short*)(ws + 5 * SEG + (size_t)O3 * CIN * 2);

  k_transpose_x<<<dim3(32, 8, 8), 256, 0, stream>>>(x, xT);
  k_cvt_w<<<dim3(1024), 256, 0, stream>>>(w_qkv, w_out, wq_bf, wo_bf);
  k_qkv<<<dim3(16, 12, 8), 256, 0, stream>>>(xT, wq_bf, Qt, Kt, Vt);
  k_attn<<<dim3(16, 64), 256, 0, stream>>>(Qt, Kt, Vt, AO);
  k_proj<<<dim3(4, 16, 8), 256, 0, stream>>>(wo_bf, AO, b_out, y);
}